// Round 5
// baseline (336.611 us; speedup 1.0000x reference)
//
#include <hip/hip_runtime.h>
#include <math.h>

#define R_BINS 64
#define Z_BINS 64
#define NBINS (R_BINS * Z_BINS)
#define BLOCK 512
#define GRID 1024

static constexpr float DR     = 10.0f / 64.0f;   // 0.15625 (exact in fp32)
static constexpr float DZ     = 4.0f  / 64.0f;   // 0.0625  (exact in fp32)
static constexpr float INV_DR = 6.4f;
static constexpr float INV_DZ = 16.0f;

// Native vector type so __builtin_nontemporal_load applies (float4 is a
// struct; the builtin needs a scalar/vector type).
typedef float f4v __attribute__((ext_vector_type(4)));

__device__ __forceinline__ f4v ntload4(const f4v* __restrict__ p) {
    return __builtin_nontemporal_load(p);
}

__device__ __forceinline__ void bin1(float x, float y, float z, float m,
                                     float* __restrict__ lbins) {
    const float r = sqrtf(x * x + y * y);
    const int i = (int)(r * INV_DR);              // r >= 0, trunc == floor
    const int j = (int)floorf((z + 2.0f) * INV_DZ);
    if (i < R_BINS && (unsigned)j < (unsigned)Z_BINS) {
        atomicAdd(&lbins[i * Z_BINS + j], m);
    }
}

// v6: cache-policy probe. Five structurally different schedules across two
// data-return paths (VGPR loads, global_load_lds DMA) all pin at
// 268 MB / ~119 us = 2.25 TB/s with every CU pipe <13% busy -> service-rate
// limit in the read path. The input footprint (268.4 MB) sits exactly at L3
// capacity and FETCH_SIZE shows a 50/50 HBM/L3 split: suspect the
// at-capacity streaming L3 interaction. This version marks both input
// streams non-temporal (nt) to minimize cache allocation/disturbance.
// Structure is otherwise the proven grid-stride register-local version.
__global__ __launch_bounds__(BLOCK) void hist_kernel(const f4v* __restrict__ pos4,
                                                     const f4v* __restrict__ mass4,
                                                     float* __restrict__ gbins,
                                                     int ngroups) {
    __shared__ float lbins[NBINS];                // 16 KB

    for (int b = threadIdx.x; b < NBINS; b += BLOCK) lbins[b] = 0.0f;
    __syncthreads();

    const int total = gridDim.x * BLOCK;
#pragma unroll 2
    for (int g = blockIdx.x * BLOCK + threadIdx.x; g < ngroups; g += total) {
        const size_t gb = (size_t)g * 3;
        const f4v q0 = ntload4(pos4 + gb);
        const f4v q1 = ntload4(pos4 + gb + 1);
        const f4v q2 = ntload4(pos4 + gb + 2);
        const f4v m  = ntload4(mass4 + g);

        bin1(q0.x, q0.y, q0.z, m.x, lbins);
        bin1(q0.w, q1.x, q1.y, m.y, lbins);
        bin1(q1.z, q1.w, q2.x, m.z, lbins);
        bin1(q2.y, q2.z, q2.w, m.w, lbins);
    }

    __syncthreads();
    // Skip-zero atomic drain (measured free in round 0: overlaps fully).
    for (int b = threadIdx.x; b < NBINS; b += BLOCK) {
        const float v = lbins[b];
        if (v != 0.0f) atomicAdd(&gbins[b], v);
    }
}

// Tail for n % 4 != 0 (not hit at N=16777216; kept for robustness).
__global__ void tail_kernel(const float* __restrict__ pos,
                            const float* __restrict__ mass,
                            float* __restrict__ gbins,
                            int start, int n) {
    const int t = start + blockIdx.x * blockDim.x + threadIdx.x;
    if (t < n) {
        const float x = pos[3 * t], y = pos[3 * t + 1], z = pos[3 * t + 2];
        const float r = sqrtf(x * x + y * y);
        const int i = (int)(r * INV_DR);
        const int j = (int)floorf((z + 2.0f) * INV_DZ);
        if (i < R_BINS && (unsigned)j < (unsigned)Z_BINS) {
            atomicAdd(&gbins[i * Z_BINS + j], mass[t]);
        }
    }
}

__global__ __launch_bounds__(256) void finalize_kernel(const float* __restrict__ gbins,
                                                       float* __restrict__ out) {
    const int idx = blockIdx.x * blockDim.x + threadIdx.x;
    if (idx < NBINS) {
        const int i = idx / Z_BINS;
        const float r0 = (float)i * DR;
        const float r1 = (float)(i + 1) * DR;
        const float area = (float)M_PI * (r1 * r1 - r0 * r0);
        out[idx] = gbins[idx] / (area * DZ);
    }
}

extern "C" void kernel_launch(void* const* d_in, const int* in_sizes, int n_in,
                              void* d_out, int out_size, void* d_ws, size_t ws_size,
                              hipStream_t stream) {
    const float* positions = (const float*)d_in[0];  // (N,3) interleaved xyz
    const float* masses    = (const float*)d_in[1];  // (N,)
    float* out   = (float*)d_out;                    // (64*64,)
    float* gbins = (float*)d_ws;                     // 16 KB accumulator

    const int n = in_sizes[1];
    const int ngroups = n / 4;                       // 4 particles (48 B) / group
    const int rem = n - ngroups * 4;

    // d_ws is re-poisoned to 0xAA before every timed call — zero it.
    hipMemsetAsync(gbins, 0, NBINS * sizeof(float), stream);

    hist_kernel<<<GRID, BLOCK, 0, stream>>>((const f4v*)positions,
                                            (const f4v*)masses,
                                            gbins, ngroups);
    if (rem > 0) {
        tail_kernel<<<(rem + 255) / 256, 256, 0, stream>>>(positions, masses,
                                                           gbins, ngroups * 4, n);
    }
    finalize_kernel<<<(NBINS + 255) / 256, 256, 0, stream>>>(gbins, out);
}